// Round 5
// baseline (617.504 us; speedup 1.0000x reference)
//
#include <hip/hip_runtime.h>
#include <math.h>

typedef __attribute__((ext_vector_type(8))) short bf8v;
typedef __attribute__((ext_vector_type(4))) float f4v;

#define B_      8
#define CIN_    256
#define C_      128
#define NPIX_   16384
#define EPS_    1e-12f
#define BN_EPS_ 1e-5f

// workspace byte offsets (all 256-aligned)
#define OFF_WK1  0u          // 128x256 bf16 = 65536 B
#define OFF_WV   65536u
#define OFF_WQ1  131072u
#define OFF_WK2  196608u     // 128x128 bf16 = 32768 B
#define OFF_WQ2  229376u
#define OFF_BIAS 262144u     // 5*128 f32 = 2560 B  [bk1,bv,bq1,bk2,bq2]
#define OFF_S    264704u     // 8*128*128 f32 = 524288 B
#define OFF_Z    788992u     // 8*128 f32 = 4096 B
#define OFF_SBF  793088u     // 8*128*128 bf16 = 262144 B

__device__ __forceinline__ unsigned short f2bf(float f) {
    unsigned u = __float_as_uint(f);
    unsigned r = u + 0x7fffu + ((u >> 16) & 1u);
    return (unsigned short)(r >> 16);
}
__device__ __forceinline__ float lo16(unsigned v){ return __uint_as_float(v << 16); }
__device__ __forceinline__ float hi16(unsigned v){ return __uint_as_float(v & 0xffff0000u); }
__device__ __forceinline__ float softplus_f(float x) {
    return fmaxf(x, 0.f) + __logf(1.f + __expf(-fabsf(x)));
}
__device__ __forceinline__ f4v MFMA(bf8v a, bf8v b, f4v c) {
    return __builtin_amdgcn_mfma_f32_16x16x32_bf16(a, b, c, 0, 0, 0);
}

struct PrepPtrs {
    const float* w[5];
    const float* g[5];
    const float* be[5];
    const float* mu[5];
    const float* va[5];
    unsigned short* wout[5];
    float* bout[5];
};

// Fold BN into weights (bf16) + bias (f32). order: 0=k1,1=v,2=q1 (cin=256), 3=k2,4=q2 (cin=128)
__global__ void prep_kernel(PrepPtrs p) {
    int idx = blockIdx.x * 256 + threadIdx.x;
    if (idx < 131072) {
        int conv, local, sh;
        if (idx < 32768)       { conv = 0; local = idx;          sh = 8; }
        else if (idx < 65536)  { conv = 1; local = idx - 32768;  sh = 8; }
        else if (idx < 98304)  { conv = 2; local = idx - 65536;  sh = 8; }
        else if (idx < 114688) { conv = 3; local = idx - 98304;  sh = 7; }
        else                   { conv = 4; local = idx - 114688; sh = 7; }
        int o = local >> sh;
        float scale = p.g[conv][o] * rsqrtf(p.va[conv][o] + BN_EPS_);
        p.wout[conv][local] = f2bf(p.w[conv][local] * scale);
    } else if (idx < 131712) {
        int j = idx - 131072;
        int conv = j >> 7;
        int o = j & 127;
        float scale = p.g[conv][o] * rsqrtf(p.va[conv][o] + BN_EPS_);
        p.bout[conv][o] = p.be[conv][o] - p.mu[conv][o] * scale;
    }
}

// ---------------- source branch FUSED: x -> (k_h, val, key) -> S += val.key^T, Z += rowsum(key)
// grid (64, 8) x 512 threads (8 waves): same 512 blocks as best config (atomics/refetch
// unchanged) but 16 waves/CU resident (4/SIMD) instead of 8 -> 2x latency hiding.
// Each wave: 16-row strip in P1/P2, 64x32 S-subtile (sAcc[4][2]=32 VGPR).
__global__ __launch_bounds__(512, 4)
void srcS(const float* __restrict__ src,
          const unsigned short* __restrict__ Wk1, const unsigned short* __restrict__ Wv,
          const unsigned short* __restrict__ Wk2, const float* __restrict__ bias,
          float* __restrict__ Sbuf, float* __restrict__ Zbuf)
{
    __shared__ __align__(16) char smem[52224];
    unsigned short* xT = (unsigned short*)smem;            // [64 n][264 us] (256 k + 8 pad)
    unsigned short* hT = (unsigned short*)(smem + 33792);  // [64 n][136 us]; region 18432B
    unsigned short* stgV = xT;                             // [128 c][72 us] aliases xT
    unsigned short* stgK = hT;                             // [128 c][72 us] aliases hT region

    const int tid = threadIdx.x;
    const int L = tid & 63, w = tid >> 6;      // w in 0..7
    const int lr = L & 15, qd = L >> 4;
    const int b = blockIdx.y;
    const int m0 = w * 16;                     // 16-row output strip per wave
    const int kbq = qd * 8;
    const int m0s = (w & 1) * 64, n0s = (w >> 1) * 32;  // 64x32 S-subtile per wave
    const float* bk1 = bias + 0;
    const float* bvp = bias + 128;
    const float* bk2 = bias + 384;

    f4v zz = {0.f, 0.f, 0.f, 0.f};
    f4v sAcc[4][2];
    #pragma unroll
    for (int mt = 0; mt < 4; mt++)
        #pragma unroll
        for (int nt = 0; nt < 2; nt++) sAcc[mt][nt] = zz;
    float zacc = 0.f;
    const int zc = tid >> 2, zh = tid & 3;

    for (int wd = 0; wd < 4; wd++) {
        const int gn0 = blockIdx.x * 256 + wd * 64;

        // stage xT: full K=256, transpose fp32->bf16 (512 threads, 2 iters)
        #pragma unroll
        for (int s = 0; s < 2; s++) {
            int id = tid + s * 512;
            int n4 = (id & 15) * 4;
            int k0 = (id >> 4) * 4;
            float4 r[4];
            #pragma unroll
            for (int i = 0; i < 4; i++)
                r[i] = *(const float4*)(src + (size_t)(b * 256 + k0 + i) * NPIX_ + gn0 + n4);
            #pragma unroll
            for (int j = 0; j < 4; j++) {
                ushort4 t;
                t.x = f2bf(((const float*)&r[0])[j]);
                t.y = f2bf(((const float*)&r[1])[j]);
                t.z = f2bf(((const float*)&r[2])[j]);
                t.w = f2bf(((const float*)&r[3])[j]);
                *(ushort4*)(xT + (n4 + j) * 264 + k0) = t;
            }
        }
        __syncthreads();

        // P1: h = Wk1*x, val = Wv*x (dual GEMM sharing B frags); 1x4 tile per wave
        f4v hAcc[4], vAcc[4];
        #pragma unroll
        for (int nt = 0; nt < 4; nt++) { hAcc[nt] = zz; vAcc[nt] = zz; }
        #pragma unroll
        for (int ks = 0; ks < 8; ks++) {
            const int kb = ks * 32 + kbq;
            bf8v a1 = *(const bf8v*)(Wk1 + (m0 + lr) * 256 + kb);
            bf8v a2 = *(const bf8v*)(Wv  + (m0 + lr) * 256 + kb);
            bf8v bx[4];
            #pragma unroll
            for (int nt = 0; nt < 4; nt++)
                bx[nt] = *(const bf8v*)(xT + (nt * 16 + lr) * 264 + kb);
            #pragma unroll
            for (int nt = 0; nt < 4; nt++) {
                hAcc[nt] = MFMA(a1, bx[nt], hAcc[nt]);
                vAcc[nt] = MFMA(a2, bx[nt], vAcc[nt]);
            }
        }
        // h epilogue: bias+relu -> hT[n][c] (bf16)
        {
            const float4 b4 = *(const float4*)(bk1 + m0 + qd * 4);
            #pragma unroll
            for (int nt = 0; nt < 4; nt++) {
                ushort4 t;
                t.x = f2bf(fmaxf(hAcc[nt][0] + b4.x, 0.f));
                t.y = f2bf(fmaxf(hAcc[nt][1] + b4.y, 0.f));
                t.z = f2bf(fmaxf(hAcc[nt][2] + b4.z, 0.f));
                t.w = f2bf(fmaxf(hAcc[nt][3] + b4.w, 0.f));
                *(ushort4*)(hT + (nt * 16 + lr) * 136 + m0 + qd * 4) = t;
            }
        }
        __syncthreads();
        // val bias+relu in regs
        {
            const float4 b4 = *(const float4*)(bvp + m0 + qd * 4);
            const float* bp = (const float*)&b4;
            #pragma unroll
            for (int nt = 0; nt < 4; nt++)
                #pragma unroll
                for (int r = 0; r < 4; r++)
                    vAcc[nt][r] = fmaxf(vAcc[nt][r] + bp[r], 0.f);
        }

        // P2: key = Wk2 * h
        f4v kAcc[4];
        #pragma unroll
        for (int nt = 0; nt < 4; nt++) kAcc[nt] = zz;
        #pragma unroll
        for (int ks = 0; ks < 4; ks++) {
            const int kb = ks * 32 + kbq;
            bf8v a = *(const bf8v*)(Wk2 + (m0 + lr) * 128 + kb);
            bf8v bh[4];
            #pragma unroll
            for (int nt = 0; nt < 4; nt++)
                bh[nt] = *(const bf8v*)(hT + (nt * 16 + lr) * 136 + kb);
            #pragma unroll
            for (int nt = 0; nt < 4; nt++)
                kAcc[nt] = MFMA(a, bh[nt], kAcc[nt]);
        }
        __syncthreads();  // hT reads done; xT reads long done

        // stage val -> xT region, key -> hT region, layout [c][72us]
        {
            const float4 b4 = *(const float4*)(bk2 + m0 + qd * 4);
            const float* bp = (const float*)&b4;
            #pragma unroll
            for (int nt = 0; nt < 4; nt++)
                #pragma unroll
                for (int r = 0; r < 4; r++) {
                    int m = m0 + qd * 4 + r;
                    stgV[m * 72 + nt * 16 + lr] = f2bf(vAcc[nt][r]);
                    stgK[m * 72 + nt * 16 + lr] = f2bf(softplus_f(kAcc[nt][r] + bp[r]));
                }
        }
        __syncthreads();

        // Z partial from this key window (each thread: 16 px of one channel)
        {
            const unsigned short* kr = stgK + zc * 72 + zh * 16;
            #pragma unroll
            for (int p = 0; p < 2; p++) {
                uint4 t = *(const uint4*)(kr + p * 8);
                zacc += lo16(t.x) + hi16(t.x) + lo16(t.y) + hi16(t.y)
                      + lo16(t.z) + hi16(t.z) + lo16(t.w) + hi16(t.w);
            }
        }
        // S partial: sAcc += val . key^T over this window's 64 pixels
        #pragma unroll
        for (int kk = 0; kk < 2; kk++) {
            const int kb = kk * 32 + kbq;
            bf8v a[4], bb[2];
            #pragma unroll
            for (int mt = 0; mt < 4; mt++)
                a[mt] = *(const bf8v*)(stgV + (m0s + mt * 16 + lr) * 72 + kb);
            #pragma unroll
            for (int nt = 0; nt < 2; nt++)
                bb[nt] = *(const bf8v*)(stgK + (n0s + nt * 16 + lr) * 72 + kb);
            #pragma unroll
            for (int mt = 0; mt < 4; mt++)
                #pragma unroll
                for (int nt = 0; nt < 2; nt++)
                    sAcc[mt][nt] = MFMA(a[mt], bb[nt], sAcc[mt][nt]);
        }
        __syncthreads();  // stgV/stgK reads done before next window's xT stage
    }

    // commit partials
    #pragma unroll
    for (int mt = 0; mt < 4; mt++)
        #pragma unroll
        for (int nt = 0; nt < 2; nt++)
            #pragma unroll
            for (int r = 0; r < 4; r++) {
                int m = m0s + mt * 16 + qd * 4 + r;
                int cN = n0s + nt * 16 + lr;
                atomicAdd(Sbuf + ((size_t)b * 128 + m) * 128 + cN, sAcc[mt][nt][r]);
            }
    atomicAdd(Zbuf + b * 128 + zc, zacc);
}

__global__ void cvts(const float* __restrict__ Sbuf, unsigned short* __restrict__ Sbf) {
    int i = blockIdx.x * 256 + threadIdx.x;
    if (i < 131072) Sbf[i] = f2bf(Sbuf[i]);
}

// ---------------- target branch fused: q1 -> q2 -> S.q / max(Z.q,eps) ----------------
// grid (128, 8) x 512 threads (8 waves), 2 windows of 64 px per block.
__global__ __launch_bounds__(512, 4)
void tgtAttn(const float* __restrict__ tgt,
             const unsigned short* __restrict__ Wq1, const unsigned short* __restrict__ Wq2,
             const float* __restrict__ bias, const unsigned short* __restrict__ Sbf,
             const float* __restrict__ Zbuf, float* __restrict__ out)
{
    __shared__ __align__(16) char smem[51968];
    unsigned short* xT = (unsigned short*)smem;            // [64][264]
    unsigned short* qT = (unsigned short*)(smem + 33792);  // [64][136] holds q_h then query
    float* dn  = (float*)(smem + 33792 + 17408);           // [64]
    float* Zsh = dn + 64;                                  // [128]

    const int tid = threadIdx.x;
    const int L = tid & 63, w = tid >> 6;      // w in 0..7
    const int lr = L & 15, qd = L >> 4;
    const int b = blockIdx.y;
    const int m0 = w * 16;
    const int kbq = qd * 8;
    const float* bq1 = bias + 256;
    const float* bq2 = bias + 512;
    f4v zz = {0.f, 0.f, 0.f, 0.f};

    if (tid < 128) Zsh[tid] = Zbuf[b * 128 + tid];

    for (int wd = 0; wd < 2; wd++) {
        const int gn0 = blockIdx.x * 128 + wd * 64;

        // stage xT (512 threads, 2 iters)
        #pragma unroll
        for (int s = 0; s < 2; s++) {
            int id = tid + s * 512;
            int n4 = (id & 15) * 4;
            int k0 = (id >> 4) * 4;
            float4 r[4];
            #pragma unroll
            for (int i = 0; i < 4; i++)
                r[i] = *(const float4*)(tgt + (size_t)(b * 256 + k0 + i) * NPIX_ + gn0 + n4);
            #pragma unroll
            for (int j = 0; j < 4; j++) {
                ushort4 t;
                t.x = f2bf(((const float*)&r[0])[j]);
                t.y = f2bf(((const float*)&r[1])[j]);
                t.z = f2bf(((const float*)&r[2])[j]);
                t.w = f2bf(((const float*)&r[3])[j]);
                *(ushort4*)(xT + (n4 + j) * 264 + k0) = t;
            }
        }
        __syncthreads();

        // P1: q_h = relu(Wq1*x + b); 1x4 tile per wave
        f4v acc1[4];
        #pragma unroll
        for (int nt = 0; nt < 4; nt++) acc1[nt] = zz;
        #pragma unroll
        for (int ks = 0; ks < 8; ks++) {
            const int kb = ks * 32 + kbq;
            bf8v a = *(const bf8v*)(Wq1 + (m0 + lr) * 256 + kb);
            bf8v bx[4];
            #pragma unroll
            for (int nt = 0; nt < 4; nt++)
                bx[nt] = *(const bf8v*)(xT + (nt * 16 + lr) * 264 + kb);
            #pragma unroll
            for (int nt = 0; nt < 4; nt++)
                acc1[nt] = MFMA(a, bx[nt], acc1[nt]);
        }
        {
            const float4 b4 = *(const float4*)(bq1 + m0 + qd * 4);
            #pragma unroll
            for (int nt = 0; nt < 4; nt++) {
                ushort4 t;
                t.x = f2bf(fmaxf(acc1[nt][0] + b4.x, 0.f));
                t.y = f2bf(fmaxf(acc1[nt][1] + b4.y, 0.f));
                t.z = f2bf(fmaxf(acc1[nt][2] + b4.z, 0.f));
                t.w = f2bf(fmaxf(acc1[nt][3] + b4.w, 0.f));
                *(ushort4*)(qT + (nt * 16 + lr) * 136 + m0 + qd * 4) = t;
            }
        }
        __syncthreads();

        // P2: query = softplus(Wq2*q_h + b)
        f4v acc2[4];
        #pragma unroll
        for (int nt = 0; nt < 4; nt++) acc2[nt] = zz;
        #pragma unroll
        for (int ks = 0; ks < 4; ks++) {
            const int kb = ks * 32 + kbq;
            bf8v a = *(const bf8v*)(Wq2 + (m0 + lr) * 128 + kb);
            bf8v bh[4];
            #pragma unroll
            for (int nt = 0; nt < 4; nt++)
                bh[nt] = *(const bf8v*)(qT + (nt * 16 + lr) * 136 + kb);
            #pragma unroll
            for (int nt = 0; nt < 4; nt++)
                acc2[nt] = MFMA(a, bh[nt], acc2[nt]);
        }
        __syncthreads();  // q_h reads done, safe to overwrite qT
        {
            const float4 b4 = *(const float4*)(bq2 + m0 + qd * 4);
            const float* bp = (const float*)&b4;
            #pragma unroll
            for (int nt = 0; nt < 4; nt++) {
                ushort4 t;
                t.x = f2bf(softplus_f(acc2[nt][0] + bp[0]));
                t.y = f2bf(softplus_f(acc2[nt][1] + bp[1]));
                t.z = f2bf(softplus_f(acc2[nt][2] + bp[2]));
                t.w = f2bf(softplus_f(acc2[nt][3] + bp[3]));
                *(ushort4*)(qT + (nt * 16 + lr) * 136 + m0 + qd * 4) = t;
            }
        }
        __syncthreads();

        // fp32 denom: dn[n] = max(sum_d Z[d]*q[d][n], eps)
        if (tid < 64) {
            const unsigned short* qr = qT + tid * 136;
            float s = 0.f;
            #pragma unroll
            for (int d = 0; d < 128; d += 8) {
                uint4 t = *(const uint4*)(qr + d);
                s = fmaf(Zsh[d + 0], lo16(t.x), s);
                s = fmaf(Zsh[d + 1], hi16(t.x), s);
                s = fmaf(Zsh[d + 2], lo16(t.y), s);
                s = fmaf(Zsh[d + 3], hi16(t.y), s);
                s = fmaf(Zsh[d + 4], lo16(t.z), s);
                s = fmaf(Zsh[d + 5], hi16(t.z), s);
                s = fmaf(Zsh[d + 6], lo16(t.w), s);
                s = fmaf(Zsh[d + 7], hi16(t.w), s);
            }
            dn[tid] = fmaxf(s, EPS_);
        }

        // P3: out = S.q
        f4v oacc[4];
        #pragma unroll
        for (int nt = 0; nt < 4; nt++) oacc[nt] = zz;
        #pragma unroll
        for (int ks = 0; ks < 4; ks++) {
            const int kb = ks * 32 + kbq;
            bf8v a = *(const bf8v*)(Sbf + (size_t)b * 16384 + (m0 + lr) * 128 + kb);
            bf8v bq[4];
            #pragma unroll
            for (int nt = 0; nt < 4; nt++)
                bq[nt] = *(const bf8v*)(qT + (nt * 16 + lr) * 136 + kb);
            #pragma unroll
            for (int nt = 0; nt < 4; nt++)
                oacc[nt] = MFMA(a, bq[nt], oacc[nt]);
        }
        __syncthreads();  // dn ready for all; qT reads done

        float inv[4];
        #pragma unroll
        for (int nt = 0; nt < 4; nt++) inv[nt] = 1.f / dn[nt * 16 + lr];
        #pragma unroll
        for (int nt = 0; nt < 4; nt++)
            #pragma unroll
            for (int r = 0; r < 4; r++) {
                int m = m0 + qd * 4 + r;
                out[(size_t)(b * 128 + m) * NPIX_ + gn0 + nt * 16 + lr] = oacc[nt][r] * inv[nt];
            }
    }
}

extern "C" void kernel_launch(void* const* d_in, const int* in_sizes, int n_in,
                              void* d_out, int out_size, void* d_ws, size_t ws_size,
                              hipStream_t stream)
{
    const float* tgt = (const float*)d_in[0];
    const float* src = (const float*)d_in[1];
    char* ws = (char*)d_ws;
    unsigned short* Wk1 = (unsigned short*)(ws + OFF_WK1);
    unsigned short* Wv  = (unsigned short*)(ws + OFF_WV);
    unsigned short* Wq1 = (unsigned short*)(ws + OFF_WQ1);
    unsigned short* Wk2 = (unsigned short*)(ws + OFF_WK2);
    unsigned short* Wq2 = (unsigned short*)(ws + OFF_WQ2);
    float* bias = (float*)(ws + OFF_BIAS);
    float* Sbuf = (float*)(ws + OFF_S);
    float* Zbuf = (float*)(ws + OFF_Z);
    unsigned short* Sbf = (unsigned short*)(ws + OFF_SBF);

    PrepPtrs p;
    p.w[0] = (const float*)d_in[4];  // k_w1
    p.w[1] = (const float*)d_in[6];  // v_w
    p.w[2] = (const float*)d_in[2];  // q_w1
    p.w[3] = (const float*)d_in[5];  // k_w2
    p.w[4] = (const float*)d_in[3];  // q_w2
    const int gbase[5] = {15, 23, 7, 19, 11}; // k1, v, q1, k2, q2 BN bases
    for (int c = 0; c < 5; c++) {
        p.g[c]  = (const float*)d_in[gbase[c]];
        p.be[c] = (const float*)d_in[gbase[c] + 1];
        p.mu[c] = (const float*)d_in[gbase[c] + 2];
        p.va[c] = (const float*)d_in[gbase[c] + 3];
    }
    p.wout[0] = Wk1; p.wout[1] = Wv; p.wout[2] = Wq1; p.wout[3] = Wk2; p.wout[4] = Wq2;
    p.bout[0] = bias; p.bout[1] = bias + 128; p.bout[2] = bias + 256;
    p.bout[3] = bias + 384; p.bout[4] = bias + 512;

    hipMemsetAsync(ws + OFF_S, 0, 524288 + 4096, stream);
    hipLaunchKernelGGL(prep_kernel, dim3(515), dim3(256), 0, stream, p);
    hipLaunchKernelGGL(srcS, dim3(64, 8), dim3(512), 0, stream,
                       src, Wk1, Wv, Wk2, bias, Sbuf, Zbuf);
    hipLaunchKernelGGL(cvts, dim3(512), dim3(256), 0, stream, Sbuf, Sbf);
    hipLaunchKernelGGL(tgtAttn, dim3(128, 8), dim3(512), 0, stream,
                       tgt, Wq1, Wq2, bias, Sbf, Zbuf, (float*)d_out);
}

// Round 7
// 457.173 us; speedup vs baseline: 1.3507x; 1.3507x over previous
//
#include <hip/hip_runtime.h>
#include <math.h>

typedef __attribute__((ext_vector_type(8))) short bf8v;
typedef __attribute__((ext_vector_type(4))) float f4v;

#define B_      8
#define CIN_    256
#define C_      128
#define NPIX_   16384
#define EPS_    1e-12f
#define BN_EPS_ 1e-5f

// workspace byte offsets (all 256-aligned)
#define OFF_WK1  0u          // 128x256 bf16 = 65536 B
#define OFF_WV   65536u
#define OFF_WQ1  131072u
#define OFF_WK2  196608u     // 128x128 bf16 = 32768 B
#define OFF_WQ2  229376u
#define OFF_BIAS 262144u     // 5*128 f32 = 2560 B  [bk1,bv,bq1,bk2,bq2]
#define OFF_S    264704u     // 8*128*128 f32 = 524288 B
#define OFF_Z    788992u     // 8*128 f32 = 4096 B  (contiguous after S)
#define OFF_VAL  793088u     // 8*128*16384 bf16 = 33554432 B
#define OFF_KEY  34347520u   // 8*128*16384 bf16 = 33554432 B

__device__ __forceinline__ unsigned short f2bf(float f) {
    unsigned u = __float_as_uint(f);
    unsigned r = u + 0x7fffu + ((u >> 16) & 1u);
    return (unsigned short)(r >> 16);
}
__device__ __forceinline__ float lo16(unsigned v){ return __uint_as_float(v << 16); }
__device__ __forceinline__ float hi16(unsigned v){ return __uint_as_float(v & 0xffff0000u); }
__device__ __forceinline__ float softplus_f(float x) {
    return fmaxf(x, 0.f) + __logf(1.f + __expf(-fabsf(x)));
}
__device__ __forceinline__ f4v MFMA(bf8v a, bf8v b, f4v c) {
    return __builtin_amdgcn_mfma_f32_16x16x32_bf16(a, b, c, 0, 0, 0);
}
__device__ __forceinline__ bf8v cvt8(const float4 lo, const float4 hi) {
    bf8v r;
    r[0] = (short)f2bf(lo.x); r[1] = (short)f2bf(lo.y);
    r[2] = (short)f2bf(lo.z); r[3] = (short)f2bf(lo.w);
    r[4] = (short)f2bf(hi.x); r[5] = (short)f2bf(hi.y);
    r[6] = (short)f2bf(hi.z); r[7] = (short)f2bf(hi.w);
    return r;
}

struct PrepPtrs {
    const float* w[5];
    const float* g[5];
    const float* be[5];
    const float* mu[5];
    const float* va[5];
    unsigned short* wout[5];
    float* bout[5];
};

// Fold BN into weights (bf16) + bias (f32); also zero Sbuf+Zbuf (132096 floats)
// so the separate memset node is not needed. grid 516 x 256 = 132096 threads.
__global__ void prep_kernel(PrepPtrs p, float* __restrict__ Sz) {
    int idx = blockIdx.x * 256 + threadIdx.x;
    if (idx < 131072) {
        int conv, local, sh;
        if (idx < 32768)       { conv = 0; local = idx;          sh = 8; }
        else if (idx < 65536)  { conv = 1; local = idx - 32768;  sh = 8; }
        else if (idx < 98304)  { conv = 2; local = idx - 65536;  sh = 8; }
        else if (idx < 114688) { conv = 3; local = idx - 98304;  sh = 7; }
        else                   { conv = 4; local = idx - 114688; sh = 7; }
        int o = local >> sh;
        float scale = p.g[conv][o] * rsqrtf(p.va[conv][o] + BN_EPS_);
        p.wout[conv][local] = f2bf(p.w[conv][local] * scale);
    } else if (idx < 131712) {
        int j = idx - 131072;
        int conv = j >> 7;
        int o = j & 127;
        float scale = p.g[conv][o] * rsqrtf(p.va[conv][o] + BN_EPS_);
        p.bout[conv][o] = p.be[conv][o] - p.mu[conv][o] * scale;
    }
    if (idx < 132096) Sz[idx] = 0.f;   // S (131072) + Z (1024)
}

// ---------------- source branch: value & key to HBM (bf16, [b][c][n]) ----------------
__global__ __launch_bounds__(256)
void srcKV(const float* __restrict__ src,
           const unsigned short* __restrict__ Wk1, const unsigned short* __restrict__ Wv,
           const unsigned short* __restrict__ Wk2, const float* __restrict__ bias,
           unsigned short* __restrict__ valg, unsigned short* __restrict__ keyg)
{
    __shared__ __align__(16) char smem[52224];
    unsigned short* xT = (unsigned short*)smem;            // [64 n][264 us] (256 k + 8 pad)
    unsigned short* hT = (unsigned short*)(smem + 33792);  // [64 n][136 us]; region 18432B

    const int tid = threadIdx.x;
    const int L = tid & 63, w = tid >> 6;
    const int lr = L & 15, qd = L >> 4;
    const int b = blockIdx.y;
    const int gn0 = blockIdx.x * 64;
    const int m0 = w * 32;
    const int kbq = qd * 8;
    const float* bk1 = bias + 0;
    const float* bvp = bias + 128;
    const float* bk2 = bias + 384;

    // stage xT: full K=256, transpose fp32->bf16
    #pragma unroll
    for (int s = 0; s < 4; s++) {
        int id = tid + s * 256;
        int n4 = (id & 15) * 4;
        int k0 = (id >> 4) * 4;
        float4 r[4];
        #pragma unroll
        for (int i = 0; i < 4; i++)
            r[i] = *(const float4*)(src + (size_t)(b * 256 + k0 + i) * NPIX_ + gn0 + n4);
        #pragma unroll
        for (int j = 0; j < 4; j++) {
            ushort4 t;
            t.x = f2bf(((const float*)&r[0])[j]);
            t.y = f2bf(((const float*)&r[1])[j]);
            t.z = f2bf(((const float*)&r[2])[j]);
            t.w = f2bf(((const float*)&r[3])[j]);
            *(ushort4*)(xT + (n4 + j) * 264 + k0) = t;
        }
    }
    __syncthreads();

    // P1: h = Wk1*x, val = Wv*x (dual GEMM sharing B frags)
    f4v zz = {0.f, 0.f, 0.f, 0.f};
    f4v hAcc[2][4], vAcc[2][4];
    #pragma unroll
    for (int mt = 0; mt < 2; mt++)
        #pragma unroll
        for (int nt = 0; nt < 4; nt++) { hAcc[mt][nt] = zz; vAcc[mt][nt] = zz; }
    #pragma unroll
    for (int ks = 0; ks < 8; ks++) {
        const int kb = ks * 32 + kbq;
        bf8v a1[2], a2[2], bx[4];
        #pragma unroll
        for (int mt = 0; mt < 2; mt++) {
            a1[mt] = *(const bf8v*)(Wk1 + (m0 + mt * 16 + lr) * 256 + kb);
            a2[mt] = *(const bf8v*)(Wv  + (m0 + mt * 16 + lr) * 256 + kb);
        }
        #pragma unroll
        for (int nt = 0; nt < 4; nt++)
            bx[nt] = *(const bf8v*)(xT + (nt * 16 + lr) * 264 + kb);
        #pragma unroll
        for (int mt = 0; mt < 2; mt++)
            #pragma unroll
            for (int nt = 0; nt < 4; nt++) {
                hAcc[mt][nt] = MFMA(a1[mt], bx[nt], hAcc[mt][nt]);
                vAcc[mt][nt] = MFMA(a2[mt], bx[nt], vAcc[mt][nt]);
            }
    }
    // h epilogue: bias+relu -> hT[n][c] (bf16)
    #pragma unroll
    for (int mt = 0; mt < 2; mt++) {
        const float4 b4 = *(const float4*)(bk1 + m0 + mt * 16 + qd * 4);
        #pragma unroll
        for (int nt = 0; nt < 4; nt++) {
            ushort4 t;
            t.x = f2bf(fmaxf(hAcc[mt][nt][0] + b4.x, 0.f));
            t.y = f2bf(fmaxf(hAcc[mt][nt][1] + b4.y, 0.f));
            t.z = f2bf(fmaxf(hAcc[mt][nt][2] + b4.z, 0.f));
            t.w = f2bf(fmaxf(hAcc[mt][nt][3] + b4.w, 0.f));
            *(ushort4*)(hT + (nt * 16 + lr) * 136 + m0 + mt * 16 + qd * 4) = t;
        }
    }
    __syncthreads();
    // val bias+relu in regs
    #pragma unroll
    for (int mt = 0; mt < 2; mt++) {
        const float4 b4 = *(const float4*)(bvp + m0 + mt * 16 + qd * 4);
        const float* bp = (const float*)&b4;
        #pragma unroll
        for (int nt = 0; nt < 4; nt++)
            #pragma unroll
            for (int r = 0; r < 4; r++)
                vAcc[mt][nt][r] = fmaxf(vAcc[mt][nt][r] + bp[r], 0.f);
    }

    // P2: key = Wk2 * h
    f4v kAcc[2][4];
    #pragma unroll
    for (int mt = 0; mt < 2; mt++)
        #pragma unroll
        for (int nt = 0; nt < 4; nt++) kAcc[mt][nt] = zz;
    #pragma unroll
    for (int ks = 0; ks < 4; ks++) {
        const int kb = ks * 32 + kbq;
        bf8v a[2], bh[4];
        #pragma unroll
        for (int mt = 0; mt < 2; mt++)
            a[mt] = *(const bf8v*)(Wk2 + (m0 + mt * 16 + lr) * 128 + kb);
        #pragma unroll
        for (int nt = 0; nt < 4; nt++)
            bh[nt] = *(const bf8v*)(hT + (nt * 16 + lr) * 136 + kb);
        #pragma unroll
        for (int mt = 0; mt < 2; mt++)
            #pragma unroll
            for (int nt = 0; nt < 4; nt++)
                kAcc[mt][nt] = MFMA(a[mt], bh[nt], kAcc[mt][nt]);
    }
    __syncthreads();  // hT reads done; xT reads long done

    // stage val -> xT region, key -> hT region, layout [c][72us]
    unsigned short* stgV = xT;
    unsigned short* stgK = hT;
    #pragma unroll
    for (int mt = 0; mt < 2; mt++) {
        const float4 b4 = *(const float4*)(bk2 + m0 + mt * 16 + qd * 4);
        const float* bp = (const float*)&b4;
        #pragma unroll
        for (int nt = 0; nt < 4; nt++)
            #pragma unroll
            for (int r = 0; r < 4; r++) {
                int m = m0 + mt * 16 + qd * 4 + r;
                stgV[m * 72 + nt * 16 + lr] = f2bf(vAcc[mt][nt][r]);
                stgK[m * 72 + nt * 16 + lr] = f2bf(softplus_f(kAcc[mt][nt][r] + bp[r]));
            }
    }
    __syncthreads();
    // coalesced copy-out: 2 arrays x 128 rows x 8 x 16B segs
    #pragma unroll
    for (int s = 0; s < 8; s++) {
        int id = tid + s * 256;
        int arr = id >> 10, rem = id & 1023;
        int c = rem >> 3, o = rem & 7;
        const unsigned short* sp = (arr ? stgK : stgV) + c * 72 + o * 8;
        uint4 d = *(const uint4*)sp;
        unsigned short* gp = (arr ? keyg : valg) + (size_t)(b * 128 + c) * NPIX_ + gn0 + o * 8;
        *(uint4*)gp = d;
    }
}

// ---------------- S = val . key^T (split-K over pixels), Z = rowsum(key) ----------------
__global__ __launch_bounds__(256)
void skern(const unsigned short* __restrict__ valg, const unsigned short* __restrict__ keyg,
           float* __restrict__ Sbuf, float* __restrict__ Zbuf)
{
    __shared__ __align__(16) unsigned short vs[128 * 72];
    __shared__ __align__(16) unsigned short ks_[128 * 72];
    const int tid = threadIdx.x;
    const int L = tid & 63, w = tid >> 6;
    const int lr = L & 15, qd = L >> 4;
    const int b = blockIdx.x >> 5, ch = blockIdx.x & 31;
    const size_t nbase = (size_t)ch * 512;
    const int m0 = (w & 1) * 64, n0 = (w >> 1) * 64;

    f4v zz = {0.f, 0.f, 0.f, 0.f};
    f4v acc[4][4];
    #pragma unroll
    for (int mt = 0; mt < 4; mt++)
        #pragma unroll
        for (int nt = 0; nt < 4; nt++) acc[mt][nt] = zz;
    float zacc = 0.f;
    const int zc = tid >> 1, zh = tid & 1;

    for (int wd = 0; wd < 8; wd++) {
        const size_t nw = nbase + wd * 64;
        #pragma unroll
        for (int s = 0; s < 8; s++) {
            int id = tid + s * 256;
            int arr = id >> 10, rem = id & 1023;
            int c = rem >> 3, o = rem & 7;
            const unsigned short* g = (arr ? keyg : valg) + (size_t)(b * 128 + c) * NPIX_ + nw + o * 8;
            uint4 d = *(const uint4*)g;
            *(uint4*)((arr ? ks_ : vs) + c * 72 + o * 8) = d;
        }
        __syncthreads();
        #pragma unroll
        for (int kk = 0; kk < 2; kk++) {
            const int kb = kk * 32 + qd * 8;
            bf8v a[4], bb[4];
            #pragma unroll
            for (int mt = 0; mt < 4; mt++)
                a[mt] = *(const bf8v*)(vs + (m0 + mt * 16 + lr) * 72 + kb);
            #pragma unroll
            for (int nt = 0; nt < 4; nt++)
                bb[nt] = *(const bf8v*)(ks_ + (n0 + nt * 16 + lr) * 72 + kb);
            #pragma unroll
            for (int mt = 0; mt < 4; mt++)
                #pragma unroll
                for (int nt = 0; nt < 4; nt++)
                    acc[mt][nt] = MFMA(a[mt], bb[nt], acc[mt][nt]);
        }
        // Z partial from this key window
        {
            const unsigned short* kr = ks_ + zc * 72 + zh * 32;
            #pragma unroll
            for (int p = 0; p < 4; p++) {
                uint4 t = *(const uint4*)(kr + p * 8);
                zacc += lo16(t.x) + hi16(t.x) + lo16(t.y) + hi16(t.y)
                      + lo16(t.z) + hi16(t.z) + lo16(t.w) + hi16(t.w);
            }
        }
        __syncthreads();
    }
    // commit partials
    #pragma unroll
    for (int mt = 0; mt < 4; mt++)
        #pragma unroll
        for (int nt = 0; nt < 4; nt++)
            #pragma unroll
            for (int r = 0; r < 4; r++) {
                int m = m0 + mt * 16 + qd * 4 + r;
                int cN = n0 + nt * 16 + lr;
                atomicAdd(Sbuf + ((size_t)b * 128 + m) * 128 + cN, acc[mt][nt][r]);
            }
    atomicAdd(Zbuf + b * 128 + zc, zacc);
}

// ---------------- target branch fused: q1 -> q2 -> S.q / max(Z.q,eps) ----------------
// P3 reads Sbuf f32 directly (hot in L2, 512KB) and converts to bf16 in-register,
// eliminating the cvts kernel + Sbf buffer.
__global__ __launch_bounds__(256)
void tgtAttn(const float* __restrict__ tgt,
             const unsigned short* __restrict__ Wq1, const unsigned short* __restrict__ Wq2,
             const float* __restrict__ bias, const float* __restrict__ Sbuf,
             const float* __restrict__ Zbuf, float* __restrict__ out)
{
    __shared__ __align__(16) char smem[51968];
    unsigned short* xT = (unsigned short*)smem;            // [64][264]
    unsigned short* qT = (unsigned short*)(smem + 33792);  // [64][136] holds q_h then query
    float* dn  = (float*)(smem + 33792 + 17408);           // [64]
    float* Zsh = dn + 64;                                  // [128]

    const int tid = threadIdx.x;
    const int L = tid & 63, w = tid >> 6;
    const int lr = L & 15, qd = L >> 4;
    const int b = blockIdx.y;
    const int gn0 = blockIdx.x * 64;
    const int m0 = w * 32;
    const int kbq = qd * 8;
    const float* bq1 = bias + 256;
    const float* bq2 = bias + 512;

    if (tid < 128) Zsh[tid] = Zbuf[b * 128 + tid];
    #pragma unroll
    for (int s = 0; s < 4; s++) {
        int id = tid + s * 256;
        int n4 = (id & 15) * 4;
        int k0 = (id >> 4) * 4;
        float4 r[4];
        #pragma unroll
        for (int i = 0; i < 4; i++)
            r[i] = *(const float4*)(tgt + (size_t)(b * 256 + k0 + i) * NPIX_ + gn0 + n4);
        #pragma unroll
        for (int j = 0; j < 4; j++) {
            ushort4 t;
            t.x = f2bf(((const float*)&r[0])[j]);
            t.y = f2bf(((const float*)&r[1])[j]);
            t.z = f2bf(((const float*)&r[2])[j]);
            t.w = f2bf(((const float*)&r[3])[j]);
            *(ushort4*)(xT + (n4 + j) * 264 + k0) = t;
        }
    }
    __syncthreads();

    // P1: q_h = relu(Wq1*x + b)
    f4v zz = {0.f, 0.f, 0.f, 0.f};
    f4v acc1[2][4];
    #pragma unroll
    for (int mt = 0; mt < 2; mt++)
        #pragma unroll
        for (int nt = 0; nt < 4; nt++) acc1[mt][nt] = zz;
    #pragma unroll
    for (int ks = 0; ks < 8; ks++) {
        const int kb = ks * 32 + kbq;
        bf8v a[2], bx[4];
        #pragma unroll
        for (int mt = 0; mt < 2; mt++)
            a[mt] = *(const bf8v*)(Wq1 + (m0 + mt * 16 + lr) * 256 + kb);
        #pragma unroll
        for (int nt = 0; nt < 4; nt++)
            bx[nt] = *(const bf8v*)(xT + (nt * 16 + lr) * 264 + kb);
        #pragma unroll
        for (int mt = 0; mt < 2; mt++)
            #pragma unroll
            for (int nt = 0; nt < 4; nt++)
                acc1[mt][nt] = MFMA(a[mt], bx[nt], acc1[mt][nt]);
    }
    #pragma unroll
    for (int mt = 0; mt < 2; mt++) {
        const float4 b4 = *(const float4*)(bq1 + m0 + mt * 16 + qd * 4);
        #pragma unroll
        for (int nt = 0; nt < 4; nt++) {
            ushort4 t;
            t.x = f2bf(fmaxf(acc1[mt][nt][0] + b4.x, 0.f));
            t.y = f2bf(fmaxf(acc1[mt][nt][1] + b4.y, 0.f));
            t.z = f2bf(fmaxf(acc1[mt][nt][2] + b4.z, 0.f));
            t.w = f2bf(fmaxf(acc1[mt][nt][3] + b4.w, 0.f));
            *(ushort4*)(qT + (nt * 16 + lr) * 136 + m0 + mt * 16 + qd * 4) = t;
        }
    }
    __syncthreads();

    // P2: query = softplus(Wq2*q_h + b)
    f4v acc2[2][4];
    #pragma unroll
    for (int mt = 0; mt < 2; mt++)
        #pragma unroll
        for (int nt = 0; nt < 4; nt++) acc2[mt][nt] = zz;
    #pragma unroll
    for (int ks = 0; ks < 4; ks++) {
        const int kb = ks * 32 + kbq;
        bf8v a[2], bh[4];
        #pragma unroll
        for (int mt = 0; mt < 2; mt++)
            a[mt] = *(const bf8v*)(Wq2 + (m0 + mt * 16 + lr) * 128 + kb);
        #pragma unroll
        for (int nt = 0; nt < 4; nt++)
            bh[nt] = *(const bf8v*)(qT + (nt * 16 + lr) * 136 + kb);
        #pragma unroll
        for (int mt = 0; mt < 2; mt++)
            #pragma unroll
            for (int nt = 0; nt < 4; nt++)
                acc2[mt][nt] = MFMA(a[mt], bh[nt], acc2[mt][nt]);
    }
    __syncthreads();  // q_h reads done, safe to overwrite qT
    #pragma unroll
    for (int mt = 0; mt < 2; mt++) {
        const float4 b4 = *(const float4*)(bq2 + m0 + mt * 16 + qd * 4);
        const float* bp = (const float*)&b4;
        #pragma unroll
        for (int nt = 0; nt < 4; nt++) {
            ushort4 t;
            t.x = f2bf(softplus_f(acc2[mt][nt][0] + bp[0]));
            t.y = f2bf(softplus_f(acc2[mt][nt][1] + bp[1]));
            t.z = f2bf(softplus_f(acc2[mt][nt][2] + bp[2]));
            t.w = f2bf(softplus_f(acc2[mt][nt][3] + bp[3]));
            *(ushort4*)(qT + (nt * 16 + lr) * 136 + m0 + mt * 16 + qd * 4) = t;
        }
    }
    __syncthreads();

    // fp32 denom: dn[n] = max(sum_d Z[d]*q[d][n], eps)  (overlaps P3 for other waves)
    if (tid < 64) {
        const unsigned short* qr = qT + tid * 136;
        float s = 0.f;
        #pragma unroll
        for (int d = 0; d < 128; d += 8) {
            uint4 t = *(const uint4*)(qr + d);
            s = fmaf(Zsh[d + 0], lo16(t.x), s);
            s = fmaf(Zsh[d + 1], hi16(t.x), s);
            s = fmaf(Zsh[d + 2], lo16(t.y), s);
            s = fmaf(Zsh[d + 3], hi16(t.y), s);
            s = fmaf(Zsh[d + 4], lo16(t.z), s);
            s = fmaf(Zsh[d + 5], hi16(t.z), s);
            s = fmaf(Zsh[d + 6], lo16(t.w), s);
            s = fmaf(Zsh[d + 7], hi16(t.w), s);
        }
        dn[tid] = fmaxf(s, EPS_);
    }

    // P3: out = S.q  (A-frags: read Sbuf f32 + convert in-register)
    f4v oacc[2][4];
    #pragma unroll
    for (int mt = 0; mt < 2; mt++)
        #pragma unroll
        for (int nt = 0; nt < 4; nt++) oacc[mt][nt] = zz;
    #pragma unroll
    for (int ks = 0; ks < 4; ks++) {
        const int kb = ks * 32 + kbq;
        bf8v a[2], bq[4];
        #pragma unroll
        for (int mt = 0; mt < 2; mt++) {
            const float* srow = Sbuf + ((size_t)b * 128 + (m0 + mt * 16 + lr)) * 128 + kb;
            float4 s0 = *(const float4*)(srow);
            float4 s1 = *(const float4*)(srow + 4);
            a[mt] = cvt8(s0, s1);
        }
        #pragma unroll
        for (int nt = 0; nt < 4; nt++)
            bq[nt] = *(const bf8v*)(qT + (nt * 16 + lr) * 136 + kb);
        #pragma unroll
        for (int mt = 0; mt < 2; mt++)
            #pragma unroll
            for (int nt = 0; nt < 4; nt++)
                oacc[mt][nt] = MFMA(a[mt], bq[nt], oacc[mt][nt]);
    }
    __syncthreads();

    float inv[4];
    #pragma unroll
    for (int nt = 0; nt < 4; nt++) inv[nt] = 1.f / dn[nt * 16 + lr];
    #pragma unroll
    for (int mt = 0; mt < 2; mt++)
        #pragma unroll
        for (int nt = 0; nt < 4; nt++)
            #pragma unroll
            for (int r = 0; r < 4; r++) {
                int m = m0 + mt * 16 + qd * 4 + r;
                out[(size_t)(b * 128 + m) * NPIX_ + gn0 + nt * 16 + lr] = oacc[mt][nt][r] * inv[nt];
            }
}

extern "C" void kernel_launch(void* const* d_in, const int* in_sizes, int n_in,
                              void* d_out, int out_size, void* d_ws, size_t ws_size,
                              hipStream_t stream)
{
    const float* tgt = (const float*)d_in[0];
    const float* src = (const float*)d_in[1];
    char* ws = (char*)d_ws;
    unsigned short* Wk1 = (unsigned short*)(ws + OFF_WK1);
    unsigned short* Wv  = (unsigned short*)(ws + OFF_WV);
    unsigned short* Wq1 = (unsigned short*)(ws + OFF_WQ1);
    unsigned short* Wk2 = (unsigned short*)(ws + OFF_WK2);
    unsigned short* Wq2 = (unsigned short*)(ws + OFF_WQ2);
    float* bias = (float*)(ws + OFF_BIAS);
    float* Sbuf = (float*)(ws + OFF_S);
    float* Zbuf = (float*)(ws + OFF_Z);
    unsigned short* valg = (unsigned short*)(ws + OFF_VAL);
    unsigned short* keyg = (unsigned short*)(ws + OFF_KEY);

    PrepPtrs p;
    p.w[0] = (const float*)d_in[4];  // k_w1
    p.w[1] = (const float*)d_in[6];  // v_w
    p.w[2] = (const float*)d_in[2];  // q_w1
    p.w[3] = (const float*)d_in[5];  // k_w2
    p.w[4] = (const float*)d_in[3];  // q_w2
    const int gbase[5] = {15, 23, 7, 19, 11}; // k1, v, q1, k2, q2 BN bases
    for (int c = 0; c < 5; c++) {
        p.g[c]  = (const float*)d_in[gbase[c]];
        p.be[c] = (const float*)d_in[gbase[c] + 1];
        p.mu[c] = (const float*)d_in[gbase[c] + 2];
        p.va[c] = (const float*)d_in[gbase[c] + 3];
    }
    p.wout[0] = Wk1; p.wout[1] = Wv; p.wout[2] = Wq1; p.wout[3] = Wk2; p.wout[4] = Wq2;
    p.bout[0] = bias; p.bout[1] = bias + 128; p.bout[2] = bias + 256;
    p.bout[3] = bias + 384; p.bout[4] = bias + 512;

    hipLaunchKernelGGL(prep_kernel, dim3(516), dim3(256), 0, stream, p, Sbuf);
    hipLaunchKernelGGL(srcKV, dim3(256, 8), dim3(256), 0, stream,
                       src, Wk1, Wv, Wk2, bias, valg, keyg);
    hipLaunchKernelGGL(skern, dim3(256), dim3(256), 0, stream, valg, keyg, Sbuf, Zbuf);
    hipLaunchKernelGGL(tgtAttn, dim3(256, 8), dim3(256), 0, stream,
                       tgt, Wq1, Wq2, bias, Sbuf, Zbuf, (float*)d_out);
}